// Round 7
// baseline (2342.027 us; speedup 1.0000x reference)
//
#include <hip/hip_runtime.h>
#include <stdint.h>

#define T_TOK 1024
#define HD 2880
#define ID 2880
#define NE 16
#define NTOP 4
#define BK 64
#define NKT (HD / BK)                 // 45

#define G1_BM 128
#define G1_BN 64
#define G1_NIB (ID / G1_BN)           // 45
#define G1_NMB (T_TOK / G1_BM)        // 8
#define G1_NB (NE * G1_NIB * G1_NMB)  // 5760

#define G2_BM 256
#define G2_BN 64
#define G2_NHB (HD / G2_BN)           // 45
#define G2_NMB (T_TOK / G2_BM)        // 4
#define G2_NB (NE * G2_NHB * G2_NMB)  // 2880

typedef short bf16x8 __attribute__((ext_vector_type(8)));
typedef float f32x4 __attribute__((ext_vector_type(4)));

__device__ __forceinline__ uint4 pack8f(const float* v) {
    union { __bf16 b[8]; uint4 q; } p;
#pragma unroll
    for (int j = 0; j < 8; j++) p.b[j] = (__bf16)v[j];
    return p.q;
}
__device__ __forceinline__ unsigned short bf16bits(float f) {
    union { __bf16 b[2]; unsigned short u[2]; } p;
    p.b[0] = (__bf16)f;
    return p.u[0];
}

// ---------------- init ----------------
__global__ __launch_bounds__(256) void k_init(float* __restrict__ out, int* __restrict__ cnt) {
    int i = blockIdx.x * 256 + threadIdx.x;
    ((float4*)out)[i] = make_float4(0.f, 0.f, 0.f, 0.f);
    if (blockIdx.x == 0 && threadIdx.x < NE) cnt[threadIdx.x] = 0;
}

// ---------------- x -> bf16 ----------------
__global__ __launch_bounds__(256) void k_xbf(const float* __restrict__ x, unsigned short* __restrict__ xbf) {
    const size_t i = (size_t)blockIdx.x * 256 + threadIdx.x;
    float v[8];
    float4 a = ((const float4*)x)[i * 2];
    float4 b = ((const float4*)x)[i * 2 + 1];
    v[0] = a.x; v[1] = a.y; v[2] = a.z; v[3] = a.w;
    v[4] = b.x; v[5] = b.y; v[6] = b.z; v[7] = b.w;
    ((uint4*)xbf)[i] = pack8f(v);
}

// ---------------- router ----------------
__global__ __launch_bounds__(256) void k_router(
    const float* __restrict__ x, const float* __restrict__ rw, const float* __restrict__ rb,
    float* __restrict__ topw, int* __restrict__ cnt, int* __restrict__ list)
{
    const int t = blockIdx.x;
    const int tid = threadIdx.x;
    float acc[NE];
#pragma unroll
    for (int e = 0; e < NE; e++) acc[e] = 0.f;
    for (int c = tid; c < HD; c += 256) {
        float xv = x[(size_t)t * HD + c];
#pragma unroll
        for (int e = 0; e < NE; e++) acc[e] += xv * rw[(size_t)e * HD + c];
    }
    __shared__ float red[4][NE];
    const int lane = tid & 63, wv = tid >> 6;
#pragma unroll
    for (int e = 0; e < NE; e++) {
        float v = acc[e];
#pragma unroll
        for (int off = 32; off > 0; off >>= 1) v += __shfl_down(v, off, 64);
        if (lane == 0) red[wv][e] = v;
    }
    __syncthreads();
    if (tid == 0) {
        float p[NE];
        float mx = -1e30f;
        for (int e = 0; e < NE; e++) {
            float v = red[0][e] + red[1][e] + red[2][e] + red[3][e] + rb[e];
            p[e] = v; mx = fmaxf(mx, v);
        }
        for (int e = 0; e < NE; e++) p[e] = expf(p[e] - mx);
        int sel[NTOP]; float pw[NTOP]; float ssum = 0.f;
        for (int k = 0; k < NTOP; k++) {
            float best = -1.f; int bi = 0;
            for (int e = 0; e < NE; e++)
                if (p[e] > best) { best = p[e]; bi = e; }
            sel[k] = bi; pw[k] = best; ssum += best; p[bi] = -2.f;
        }
        for (int k = 0; k < NTOP; k++) {
            topw[t * NTOP + k] = pw[k] / ssum;
            int e = sel[k];
            int pos = atomicAdd(&cnt[e], 1);
            list[e * T_TOK + pos] = t * NTOP + k;
        }
    }
}

// ---------------- prefix scan ----------------
__global__ void k_scan(const int* __restrict__ cnt, int* __restrict__ offs) {
    if (threadIdx.x == 0 && blockIdx.x == 0) {
        int s = 0;
        for (int e = 0; e < NE; e++) { offs[e] = s; s += cnt[e]; }
        offs[NE] = s;
    }
}

// ---------------- GEMM1: A from global(L1), W dbuf LDS, 64m wave tiles ----------------
__global__ __launch_bounds__(512, 4) void k_gemm1(
    const unsigned short* __restrict__ xbf,
    const float* __restrict__ wg, const float* __restrict__ bg,
    const float* __restrict__ wu, const float* __restrict__ bu,
    const int* __restrict__ cnt, const int* __restrict__ offs,
    const int* __restrict__ list,
    unsigned short* __restrict__ act)
{
    const int lin = blockIdx.x;
    const int logical = (lin & 7) * (G1_NB / 8) + (lin >> 3);
    const int mblk = logical & 7;
    const int iblk = (logical >> 3) % G1_NIB;
    const int e = logical / (G1_NIB * G1_NMB);

    const int count = cnt[e];
    const int m0 = mblk * G1_BM;
    if (m0 >= count) return;
    const int mcount = min(G1_BM, count - m0);
    const int i0 = iblk * G1_BN;
    const int tid = threadIdx.x;

    __shared__ __align__(16) char sW[2][2][8192];   // [buf][G/U][col64][k64 bf16, xor-swz]
    __shared__ float sgl[128][66];                  // G silu staging for epilogue
    __shared__ int lidx[G1_BM];

    if (tid < G1_BM) lidx[tid] = list[e * T_TOK + m0 + min(tid, mcount - 1)];
    __syncthreads();

    const int lane = tid & 63, wid = tid >> 6;
    const int wm = wid >> 2;          // m-half (64 rows)
    const int wn = (wid >> 1) & 1;    // n-half (32 cols)
    const int mg = wid & 1;           // which cb of this wave holds G
    const int lr = lane & 15, lk = lane >> 4;

    const unsigned short* arow[4];
#pragma unroll
    for (int mb = 0; mb < 4; mb++)
        arow[mb] = xbf + (size_t)(lidx[wm * 64 + mb * 16 + lr] >> 2) * HD;

    // W staging: tid<256 -> G, else U; 16 coalesced strided floats / thread
    const int wtid = tid & 255;
    const int wc = wtid & 63, whg = wtid >> 6;
    const float* wsrc = (tid < 256 ? wg : wu) + ((size_t)e * HD + whg * 16) * ID + i0 + wc;
    const int wmat = tid >> 8;

    f32x4 acc[4][2];
#pragma unroll
    for (int mb = 0; mb < 4; mb++)
#pragma unroll
        for (int cb = 0; cb < 2; cb++) acc[mb][cb] = (f32x4){0.f, 0.f, 0.f, 0.f};

    float wv[16];
    {   // prologue: stage tile 0
#pragma unroll
        for (int j = 0; j < 16; j++) wv[j] = wsrc[(size_t)j * ID];
        char* wd = &sW[0][wmat][0];
        *(uint4*)(wd + wc * 128 + (((whg * 2) ^ (wc & 7)) * 16)) = pack8f(wv);
        *(uint4*)(wd + wc * 128 + (((whg * 2 + 1) ^ (wc & 7)) * 16)) = pack8f(wv + 8);
    }
    __syncthreads();

    for (int kt = 0; kt < NKT; kt++) {
        const bool more = (kt + 1 < NKT);
        // A fragments FIRST (so their waits don't drain the W prefetch)
        bf16x8 af[4][2];
#pragma unroll
        for (int mb = 0; mb < 4; mb++)
#pragma unroll
            for (int ks = 0; ks < 2; ks++)
                af[mb][ks] = *(const bf16x8*)(arow[mb] + kt * BK + (ks * 4 + lk) * 8);
        // W prefetch for next tile (in flight across MFMA)
        if (more) {
#pragma unroll
            for (int j = 0; j < 16; j++) wv[j] = wsrc[(size_t)((kt + 1) * BK + j) * ID];
        }
        __builtin_amdgcn_sched_barrier(0);   // pin staging-issue before MFMA
        const char* base = &sW[kt & 1][0][0];
#pragma unroll
        for (int cb = 0; cb < 2; cb++) {
            const char* mbase = base + ((cb ^ mg) ? 8192 : 0);
            const int ii = wn * 32 + cb * 16 + lr;
#pragma unroll
            for (int ks = 0; ks < 2; ks++) {
                const int s = ks * 4 + lk;
                bf16x8 bf = *(const bf16x8*)(mbase + ii * 128 + ((s ^ (ii & 7)) * 16));
#pragma unroll
                for (int mb = 0; mb < 4; mb++)
                    acc[mb][cb] = __builtin_amdgcn_mfma_f32_16x16x32_bf16(af[mb][ks], bf, acc[mb][cb], 0, 0, 0);
            }
        }
        if (more) {
            char* wd = &sW[(kt + 1) & 1][wmat][0];
            *(uint4*)(wd + wc * 128 + (((whg * 2) ^ (wc & 7)) * 16)) = pack8f(wv);
            *(uint4*)(wd + wc * 128 + (((whg * 2 + 1) ^ (wc & 7)) * 16)) = pack8f(wv + 8);
        }
        __syncthreads();
    }

    const int gbase = offs[e] + m0;
    // G pass: silu(g) -> sgl
#pragma unroll
    for (int cb = 0; cb < 2; cb++) {
        if (cb == mg) {
            const int colg = wn * 32 + cb * 16 + lr;
            const float bgv = bg[e * ID + i0 + colg];
#pragma unroll
            for (int mb = 0; mb < 4; mb++)
#pragma unroll
                for (int q = 0; q < 4; q++) {
                    const int row = wm * 64 + mb * 16 + lk * 4 + q;
                    float gv = fminf(acc[mb][cb][q] + bgv, 7.0f);
                    sgl[row][colg] = gv / (1.0f + __expf(-1.702f * gv));
                }
        }
    }
    __syncthreads();
    // U pass: combine + store
#pragma unroll
    for (int cb = 0; cb < 2; cb++) {
        if (cb != mg) {
            const int colu = wn * 32 + cb * 16 + lr;
            const float buv = bu[e * ID + i0 + colu];
#pragma unroll
            for (int mb = 0; mb < 4; mb++)
#pragma unroll
                for (int q = 0; q < 4; q++) {
                    const int row = wm * 64 + mb * 16 + lk * 4 + q;
                    if (row < mcount) {
                        float uv = fminf(fmaxf(acc[mb][cb][q] + buv, -7.0f), 7.0f) + 1.0f;
                        act[(size_t)(gbase + row) * ID + i0 + colu] = bf16bits(uv * sgl[row][colu]);
                    }
                }
        }
    }
}

// ---------------- GEMM2: A from global, W dbuf LDS, BM=256 ----------------
__global__ __launch_bounds__(512, 4) void k_gemm2(
    const unsigned short* __restrict__ act,
    const float* __restrict__ wd, const float* __restrict__ bd,
    const float* __restrict__ topw,
    const int* __restrict__ cnt, const int* __restrict__ offs,
    const int* __restrict__ list,
    float* __restrict__ out)
{
    const int lin = blockIdx.x;
    const int logical = (lin & 7) * (G2_NB / 8) + (lin >> 3);
    const int mblk = logical & 3;
    const int hblk = (logical >> 2) % G2_NHB;
    const int e = logical / (G2_NHB * G2_NMB);

    const int count = cnt[e];
    const int m0 = mblk * G2_BM;
    if (m0 >= count) return;
    const int mcount = min(G2_BM, count - m0);
    const int h0 = hblk * G2_BN;
    const int tid = threadIdx.x;
    const int gbase = offs[e] + m0;

    __shared__ __align__(16) char sW[2][8192];
    __shared__ int lidx[G2_BM];

    if (tid < G2_BM) lidx[tid] = list[e * T_TOK + m0 + min(tid, mcount - 1)];
    __syncthreads();

    const int lane = tid & 63, wid = tid >> 6;
    const int wm = wid >> 1, wn = wid & 1;   // 4 m-bands x 2 n-halves
    const int lr = lane & 15, lk = lane >> 4;

    const unsigned short* arow[4];
#pragma unroll
    for (int mb = 0; mb < 4; mb++)
        arow[mb] = act + (size_t)(gbase + min(wm * 64 + mb * 16 + lr, mcount - 1)) * ID;

    const int wc = tid & 63, whg = tid >> 6;   // col, k-group of 8
    const float* wsrc = wd + (size_t)e * (size_t)ID * HD + (size_t)(whg * 8) * HD + h0 + wc;

    f32x4 acc[4][2];
#pragma unroll
    for (int mb = 0; mb < 4; mb++)
#pragma unroll
        for (int cb = 0; cb < 2; cb++) acc[mb][cb] = (f32x4){0.f, 0.f, 0.f, 0.f};

    float wv[8];
    {   // prologue
#pragma unroll
        for (int j = 0; j < 8; j++) wv[j] = wsrc[(size_t)j * HD];
        *(uint4*)(sW[0] + wc * 128 + ((whg ^ (wc & 7)) * 16)) = pack8f(wv);
    }
    __syncthreads();

    for (int kt = 0; kt < NKT; kt++) {
        const bool more = (kt + 1 < NKT);
        bf16x8 af[4][2];
#pragma unroll
        for (int mb = 0; mb < 4; mb++)
#pragma unroll
            for (int ks = 0; ks < 2; ks++)
                af[mb][ks] = *(const bf16x8*)(arow[mb] + kt * BK + (ks * 4 + lk) * 8);
        if (more) {
#pragma unroll
            for (int j = 0; j < 8; j++) wv[j] = wsrc[(size_t)((kt + 1) * BK + j) * HD];
        }
        __builtin_amdgcn_sched_barrier(0);
        const char* base = sW[kt & 1];
#pragma unroll
        for (int cb = 0; cb < 2; cb++) {
            const int ii = wn * 32 + cb * 16 + lr;
#pragma unroll
            for (int ks = 0; ks < 2; ks++) {
                const int s = ks * 4 + lk;
                bf16x8 bf = *(const bf16x8*)(base + ii * 128 + ((s ^ (ii & 7)) * 16));
#pragma unroll
                for (int mb = 0; mb < 4; mb++)
                    acc[mb][cb] = __builtin_amdgcn_mfma_f32_16x16x32_bf16(af[mb][ks], bf, acc[mb][cb], 0, 0, 0);
            }
        }
        if (more) {
            *(uint4*)(sW[(kt + 1) & 1] + wc * 128 + ((whg ^ (wc & 7)) * 16)) = pack8f(wv);
        }
        __syncthreads();
    }

#pragma unroll
    for (int mb = 0; mb < 4; mb++)
#pragma unroll
        for (int cb = 0; cb < 2; cb++) {
            const int col = h0 + wn * 32 + cb * 16 + lr;
            const float bdv = bd[e * HD + col];
#pragma unroll
            for (int q = 0; q < 4; q++) {
                const int r = wm * 64 + mb * 16 + lk * 4 + q;
                if (r < mcount) {
                    int idx = lidx[r];
                    float w = topw[idx];
                    atomicAdd(&out[(size_t)(idx >> 2) * HD + col], w * (acc[mb][cb][q] + bdv));
                }
            }
        }
}

extern "C" void kernel_launch(void* const* d_in, const int* in_sizes, int n_in,
                              void* d_out, int out_size, void* d_ws, size_t ws_size,
                              hipStream_t stream)
{
    const float* x  = (const float*)d_in[0];
    const float* rw = (const float*)d_in[1];
    const float* rb = (const float*)d_in[2];
    const float* wg = (const float*)d_in[3];
    const float* bg = (const float*)d_in[4];
    const float* wu = (const float*)d_in[5];
    const float* bu = (const float*)d_in[6];
    const float* wd = (const float*)d_in[7];
    const float* bd = (const float*)d_in[8];
    float* out = (float*)d_out;

    char* ws = (char*)d_ws;
    int*   cnt  = (int*)(ws + 0);
    int*   offs = (int*)(ws + 256);
    float* topw = (float*)(ws + 1024);
    int*   list = (int*)(ws + 32768);
    unsigned short* act = (unsigned short*)(ws + 131072);                         // 4096x2880 bf16
    unsigned short* xbf = (unsigned short*)(ws + 131072 + (size_t)4096 * ID * 2); // 1024x2880 bf16

    hipLaunchKernelGGL(k_init, dim3(T_TOK * HD / 1024), dim3(256), 0, stream, out, cnt);
    hipLaunchKernelGGL(k_xbf, dim3(T_TOK * HD / (256 * 8)), dim3(256), 0, stream, x, xbf);
    hipLaunchKernelGGL(k_router, dim3(T_TOK), dim3(256), 0, stream, x, rw, rb, topw, cnt, list);
    hipLaunchKernelGGL(k_scan, dim3(1), dim3(64), 0, stream, cnt, offs);
    hipLaunchKernelGGL(k_gemm1, dim3(G1_NB), dim3(512), 0, stream,
                       xbf, wg, bg, wu, bu, cnt, offs, list, act);
    hipLaunchKernelGGL(k_gemm2, dim3(G2_NB), dim3(512), 0, stream,
                       act, wd, bd, topw, cnt, offs, list, out);
}

// Round 8
// 1507.147 us; speedup vs baseline: 1.5539x; 1.5539x over previous
//
#include <hip/hip_runtime.h>
#include <stdint.h>

#define T_TOK 1024
#define HD 2880
#define ID 2880
#define NE 16
#define NTOP 4
#define BK 64
#define NKT (HD / BK)          // 45

#define BM 128
#define BN 64
#define NIB (ID / BN)          // 45
#define NMB (T_TOK / BM)       // 8
#define NBLK (NE * NIB * NMB)  // 5760

typedef short bf16x8 __attribute__((ext_vector_type(8)));
typedef float f32x4 __attribute__((ext_vector_type(4)));

__device__ __forceinline__ uint4 pack8f(const float* v) {
    union { __bf16 b[8]; uint4 q; } p;
#pragma unroll
    for (int j = 0; j < 8; j++) p.b[j] = (__bf16)v[j];
    return p.q;
}
__device__ __forceinline__ unsigned short bf16bits(float f) {
    union { __bf16 b[2]; unsigned short u[2]; } p;
    p.b[0] = (__bf16)f;
    return p.u[0];
}

// ---------------- init ----------------
__global__ __launch_bounds__(256) void k_init(float* __restrict__ out, int* __restrict__ cnt) {
    int i = blockIdx.x * 256 + threadIdx.x;
    ((float4*)out)[i] = make_float4(0.f, 0.f, 0.f, 0.f);
    if (blockIdx.x == 0 && threadIdx.x < NE) cnt[threadIdx.x] = 0;
}

// ---------------- x -> bf16 ----------------
__global__ __launch_bounds__(256) void k_xbf(const float* __restrict__ x, unsigned short* __restrict__ xbf) {
    const size_t i = (size_t)blockIdx.x * 256 + threadIdx.x;
    float v[8];
    float4 a = ((const float4*)x)[i * 2];
    float4 b = ((const float4*)x)[i * 2 + 1];
    v[0] = a.x; v[1] = a.y; v[2] = a.z; v[3] = a.w;
    v[4] = b.x; v[5] = b.y; v[6] = b.z; v[7] = b.w;
    ((uint4*)xbf)[i] = pack8f(v);
}

// ---------------- router ----------------
__global__ __launch_bounds__(256) void k_router(
    const float* __restrict__ x, const float* __restrict__ rw, const float* __restrict__ rb,
    float* __restrict__ topw, int* __restrict__ cnt, int* __restrict__ list)
{
    const int t = blockIdx.x;
    const int tid = threadIdx.x;
    float acc[NE];
#pragma unroll
    for (int e = 0; e < NE; e++) acc[e] = 0.f;
    for (int c = tid; c < HD; c += 256) {
        float xv = x[(size_t)t * HD + c];
#pragma unroll
        for (int e = 0; e < NE; e++) acc[e] += xv * rw[(size_t)e * HD + c];
    }
    __shared__ float red[4][NE];
    const int lane = tid & 63, wv = tid >> 6;
#pragma unroll
    for (int e = 0; e < NE; e++) {
        float v = acc[e];
#pragma unroll
        for (int off = 32; off > 0; off >>= 1) v += __shfl_down(v, off, 64);
        if (lane == 0) red[wv][e] = v;
    }
    __syncthreads();
    if (tid == 0) {
        float p[NE];
        float mx = -1e30f;
        for (int e = 0; e < NE; e++) {
            float v = red[0][e] + red[1][e] + red[2][e] + red[3][e] + rb[e];
            p[e] = v; mx = fmaxf(mx, v);
        }
        for (int e = 0; e < NE; e++) p[e] = expf(p[e] - mx);
        int sel[NTOP]; float pw[NTOP]; float ssum = 0.f;
        for (int k = 0; k < NTOP; k++) {
            float best = -1.f; int bi = 0;
            for (int e = 0; e < NE; e++)
                if (p[e] > best) { best = p[e]; bi = e; }
            sel[k] = bi; pw[k] = best; ssum += best; p[bi] = -2.f;
        }
        for (int k = 0; k < NTOP; k++) {
            topw[t * NTOP + k] = pw[k] / ssum;
            int e = sel[k];
            int pos = atomicAdd(&cnt[e], 1);
            list[e * T_TOK + pos] = t * NTOP + k;
        }
    }
}

// ---------------- prefix scan ----------------
__global__ void k_scan(const int* __restrict__ cnt, int* __restrict__ offs) {
    if (threadIdx.x == 0 && blockIdx.x == 0) {
        int s = 0;
        for (int e = 0; e < NE; e++) { offs[e] = s; s += cnt[e]; }
        offs[NE] = s;
    }
}

// ---------------- GEMM1: producer waves stage W; consumer waves MFMA ----------------
__global__ __launch_bounds__(512, 4) void k_gemm1(
    const unsigned short* __restrict__ xbf,
    const float* __restrict__ wg, const float* __restrict__ bg,
    const float* __restrict__ wu, const float* __restrict__ bu,
    const int* __restrict__ cnt, const int* __restrict__ offs,
    const int* __restrict__ list,
    unsigned short* __restrict__ act)
{
    const int lin = blockIdx.x;
    const int logical = (lin & 7) * (NBLK / 8) + (lin >> 3);
    const int mblk = logical & 7;
    const int iblk = (logical >> 3) % NIB;
    const int e = logical / (NIB * NMB);

    const int count = cnt[e];
    const int m0 = mblk * BM;
    if (m0 >= count) return;
    const int mcount = min(BM, count - m0);
    const int i0 = iblk * BN;
    const int tid = threadIdx.x;

    __shared__ __align__(16) char sGU[2][2][BN * BK * 2];  // [buf][G/U] 8KB each = 32KB
    __shared__ int lidx[BM];

    if (tid < BM) lidx[tid] = list[e * T_TOK + m0 + min(tid, mcount - 1)];
    __syncthreads();

    const int lane = tid & 63, wid = tid >> 6;
    const bool producer = (wid >= 4);

    // ---- producer state ----
    const int ptid = tid & 255;
    const int wc = ptid & 63, sel = ptid >> 6;   // col, {mat,khalf}
    const int mat = sel & 1, kh = sel >> 1;
    const float* wsrc = (mat ? wu : wg) + ((size_t)e * HD + kh * 32) * ID + i0 + wc;
    char* const pdst0 = &sGU[0][mat][0] + wc * 128;
    char* const pdst1 = &sGU[1][mat][0] + wc * 128;

    // ---- consumer state ----
    const int mh = wid >> 1, nh = wid & 1;
    const int lr = lane & 15, lk = lane >> 4;
    const unsigned short* arow[4];
#pragma unroll
    for (int mb = 0; mb < 4; mb++)
        arow[mb] = xbf + (size_t)(lidx[mh * 64 + mb * 16 + lr] >> 2) * HD;

    f32x4 accG[4][2], accU[4][2];
#pragma unroll
    for (int mb = 0; mb < 4; mb++)
#pragma unroll
        for (int cb = 0; cb < 2; cb++) {
            accG[mb][cb] = (f32x4){0.f, 0.f, 0.f, 0.f};
            accU[mb][cb] = (f32x4){0.f, 0.f, 0.f, 0.f};
        }

    // prologue: producers stage tile 0
    if (producer) {
        float v[32];
#pragma unroll
        for (int j = 0; j < 32; j++) v[j] = wsrc[(size_t)j * ID];
#pragma unroll
        for (int jj = 0; jj < 4; jj++) {
            const int s = kh * 4 + jj;
            *(uint4*)(pdst0 + ((s ^ (wc & 7)) * 16)) = pack8f(v + jj * 8);
        }
    }
    __syncthreads();

    for (int kt = 0; kt < NKT; kt++) {
        if (producer) {
            if (kt + 1 < NKT) {
                const float* ws = wsrc + (size_t)(kt + 1) * BK * ID;
                float v[32];
#pragma unroll
                for (int j = 0; j < 32; j++) v[j] = ws[(size_t)j * ID];
                char* d = (kt & 1) ? pdst0 : pdst1;   // buf (kt+1)&1
#pragma unroll
                for (int jj = 0; jj < 4; jj++) {
                    const int s = kh * 4 + jj;
                    *(uint4*)(d + ((s ^ (wc & 7)) * 16)) = pack8f(v + jj * 8);
                }
            }
        } else {
            bf16x8 af[4][2];
#pragma unroll
            for (int mb = 0; mb < 4; mb++)
#pragma unroll
                for (int ks = 0; ks < 2; ks++)
                    af[mb][ks] = *(const bf16x8*)(arow[mb] + kt * BK + (ks * 4 + lk) * 8);
            const char* bG = &sGU[kt & 1][0][0];
            const char* bU = &sGU[kt & 1][1][0];
            __builtin_amdgcn_s_setprio(1);
#pragma unroll
            for (int ks = 0; ks < 2; ks++) {
                const int s = ks * 4 + lk;
#pragma unroll
                for (int cb = 0; cb < 2; cb++) {
                    const int ii = nh * 32 + cb * 16 + lr;
                    const int off = ii * 128 + ((s ^ (ii & 7)) * 16);
                    bf16x8 g = *(const bf16x8*)(bG + off);
#pragma unroll
                    for (int mb = 0; mb < 4; mb++)
                        accG[mb][cb] = __builtin_amdgcn_mfma_f32_16x16x32_bf16(af[mb][ks], g, accG[mb][cb], 0, 0, 0);
                    bf16x8 u = *(const bf16x8*)(bU + off);
#pragma unroll
                    for (int mb = 0; mb < 4; mb++)
                        accU[mb][cb] = __builtin_amdgcn_mfma_f32_16x16x32_bf16(af[mb][ks], u, accU[mb][cb], 0, 0, 0);
                }
            }
            __builtin_amdgcn_s_setprio(0);
        }
        __syncthreads();
    }

    if (producer) return;

    const int gbase = offs[e] + m0;
#pragma unroll
    for (int cb = 0; cb < 2; cb++) {
        const int col = nh * 32 + cb * 16 + lr;
        const float bgv = bg[e * ID + i0 + col];
        const float buv = bu[e * ID + i0 + col];
#pragma unroll
        for (int mb = 0; mb < 4; mb++)
#pragma unroll
            for (int q = 0; q < 4; q++) {
                const int row = mh * 64 + mb * 16 + lk * 4 + q;
                if (row < mcount) {
                    float gv = fminf(accG[mb][cb][q] + bgv, 7.0f);
                    float uv = fminf(fmaxf(accU[mb][cb][q] + buv, -7.0f), 7.0f);
                    float av = (uv + 1.0f) * (gv / (1.0f + __expf(-1.702f * gv)));
                    act[(size_t)(gbase + row) * ID + i0 + col] = bf16bits(av);
                }
            }
    }
}

// ---------------- GEMM2: producer waves stage Wd; consumer waves MFMA ----------------
__global__ __launch_bounds__(512, 4) void k_gemm2(
    const unsigned short* __restrict__ act,
    const float* __restrict__ wd, const float* __restrict__ bd,
    const float* __restrict__ topw,
    const int* __restrict__ cnt, const int* __restrict__ offs,
    const int* __restrict__ list,
    float* __restrict__ out)
{
    const int lin = blockIdx.x;
    const int logical = (lin & 7) * (NBLK / 8) + (lin >> 3);
    const int mblk = logical & 7;
    const int hblk = (logical >> 3) % NIB;
    const int e = logical / (NIB * NMB);

    const int count = cnt[e];
    const int m0 = mblk * BM;
    if (m0 >= count) return;
    const int mcount = min(BM, count - m0);
    const int h0 = hblk * BN;
    const int tid = threadIdx.x;
    const int gbase = offs[e] + m0;

    __shared__ __align__(16) char sW[2][BN * BK * 2];   // 8KB x2
    __shared__ int lidx[BM];

    if (tid < BM) lidx[tid] = list[e * T_TOK + m0 + min(tid, mcount - 1)];
    __syncthreads();

    const int lane = tid & 63, wid = tid >> 6;
    const bool producer = (wid >= 4);

    // ---- producer state ----
    const int ptid = tid & 255;
    const int wc = ptid & 63, kq = ptid >> 6;   // col, k-quarter (16 k each)
    const float* wsrc = wd + ((size_t)e * ID + kq * 16) * HD + h0 + wc;
    char* const pdst0 = &sW[0][0] + wc * 128;
    char* const pdst1 = &sW[1][0] + wc * 128;

    // ---- consumer state ----
    const int mh = wid >> 1, nh = wid & 1;
    const int lr = lane & 15, lk = lane >> 4;
    const unsigned short* arow[4];
#pragma unroll
    for (int mb = 0; mb < 4; mb++)
        arow[mb] = act + (size_t)(gbase + min(mh * 64 + mb * 16 + lr, mcount - 1)) * ID;

    f32x4 acc[4][2];
#pragma unroll
    for (int mb = 0; mb < 4; mb++)
#pragma unroll
        for (int cb = 0; cb < 2; cb++) acc[mb][cb] = (f32x4){0.f, 0.f, 0.f, 0.f};

    if (producer) {
        float v[16];
#pragma unroll
        for (int j = 0; j < 16; j++) v[j] = wsrc[(size_t)j * HD];
#pragma unroll
        for (int jj = 0; jj < 2; jj++) {
            const int s = kq * 2 + jj;
            *(uint4*)(pdst0 + ((s ^ (wc & 7)) * 16)) = pack8f(v + jj * 8);
        }
    }
    __syncthreads();

    for (int kt = 0; kt < NKT; kt++) {
        if (producer) {
            if (kt + 1 < NKT) {
                const float* ws = wsrc + (size_t)(kt + 1) * BK * HD;
                float v[16];
#pragma unroll
                for (int j = 0; j < 16; j++) v[j] = ws[(size_t)j * HD];
                char* d = (kt & 1) ? pdst0 : pdst1;
#pragma unroll
                for (int jj = 0; jj < 2; jj++) {
                    const int s = kq * 2 + jj;
                    *(uint4*)(d + ((s ^ (wc & 7)) * 16)) = pack8f(v + jj * 8);
                }
            }
        } else {
            bf16x8 af[4][2];
#pragma unroll
            for (int mb = 0; mb < 4; mb++)
#pragma unroll
                for (int ks = 0; ks < 2; ks++)
                    af[mb][ks] = *(const bf16x8*)(arow[mb] + kt * BK + (ks * 4 + lk) * 8);
            const char* bW = &sW[kt & 1][0];
            __builtin_amdgcn_s_setprio(1);
#pragma unroll
            for (int ks = 0; ks < 2; ks++) {
                const int s = ks * 4 + lk;
#pragma unroll
                for (int cb = 0; cb < 2; cb++) {
                    const int ii = nh * 32 + cb * 16 + lr;
                    bf16x8 w = *(const bf16x8*)(bW + ii * 128 + ((s ^ (ii & 7)) * 16));
#pragma unroll
                    for (int mb = 0; mb < 4; mb++)
                        acc[mb][cb] = __builtin_amdgcn_mfma_f32_16x16x32_bf16(af[mb][ks], w, acc[mb][cb], 0, 0, 0);
                }
            }
            __builtin_amdgcn_s_setprio(0);
        }
        __syncthreads();
    }

    if (producer) return;

#pragma unroll
    for (int cb = 0; cb < 2; cb++) {
        const int col = h0 + nh * 32 + cb * 16 + lr;
        const float bdv = bd[e * HD + col];
#pragma unroll
        for (int mb = 0; mb < 4; mb++)
#pragma unroll
            for (int q = 0; q < 4; q++) {
                const int r = mh * 64 + mb * 16 + lk * 4 + q;
                if (r < mcount) {
                    const int idx = lidx[r];
                    const float w = topw[idx];
                    atomicAdd(&out[(size_t)(idx >> 2) * HD + col], w * (acc[mb][cb][q] + bdv));
                }
            }
    }
}

extern "C" void kernel_launch(void* const* d_in, const int* in_sizes, int n_in,
                              void* d_out, int out_size, void* d_ws, size_t ws_size,
                              hipStream_t stream)
{
    const float* x  = (const float*)d_in[0];
    const float* rw = (const float*)d_in[1];
    const float* rb = (const float*)d_in[2];
    const float* wg = (const float*)d_in[3];
    const float* bg = (const float*)d_in[4];
    const float* wu = (const float*)d_in[5];
    const float* bu = (const float*)d_in[6];
    const float* wd = (const float*)d_in[7];
    const float* bd = (const float*)d_in[8];
    float* out = (float*)d_out;

    char* ws = (char*)d_ws;
    int*   cnt  = (int*)(ws + 0);
    int*   offs = (int*)(ws + 256);
    float* topw = (float*)(ws + 1024);
    int*   list = (int*)(ws + 32768);
    unsigned short* act = (unsigned short*)(ws + 131072);                         // 4096x2880 bf16
    unsigned short* xbf = (unsigned short*)(ws + 131072 + (size_t)4096 * ID * 2); // 1024x2880 bf16

    hipLaunchKernelGGL(k_init, dim3(T_TOK * HD / 1024), dim3(256), 0, stream, out, cnt);
    hipLaunchKernelGGL(k_xbf, dim3(T_TOK * HD / (256 * 8)), dim3(256), 0, stream, x, xbf);
    hipLaunchKernelGGL(k_router, dim3(T_TOK), dim3(256), 0, stream, x, rw, rb, topw, cnt, list);
    hipLaunchKernelGGL(k_scan, dim3(1), dim3(64), 0, stream, cnt, offs);
    hipLaunchKernelGGL(k_gemm1, dim3(NBLK), dim3(512), 0, stream,
                       xbf, wg, bg, wu, bu, cnt, offs, list, act);
    hipLaunchKernelGGL(k_gemm2, dim3(NBLK), dim3(512), 0, stream,
                       act, wd, bd, topw, cnt, offs, list, out);
}